// Round 1
// baseline (79.124 us; speedup 1.0000x reference)
//
#include <hip/hip_runtime.h>
#include <math.h>

#define GMM_K 8
#define HALF_LOG2PI 0.9189385332046727f   // 0.5 * log(2*pi)
#define LOG2E       1.4426950408889634f   // 1/ln(2)

// hscore = -0.5*(mdpdf/mpdf)^2 + ddpdf/mpdf with
//   p_k  = exp2( c1_k + c2_k * diff^2 ),  c1_k = (logw_k - 0.5*lv_k - 0.5*log2pi)*log2e
//                                          c2_k = -0.5*log2e * iv_k,  iv_k = exp(-lv_k)
//   sd   = diff * iv_k
//   mpdf = sum p ; md = sum p*sd (true mdpdf = -md, sign cancels in dln^2) ;
//   dd   = sum p*(sd^2 - iv)
//
// V2 changes vs V1 (77 us, kernel est. ~30 us):
//  - Params in SGPRs via uniform loads + readfirstlane. No LDS, no __syncthreads,
//    no divergent prologue. Inner-loop ops read <=1 SGPR each -> feed VALU directly.
//  - Split-half layout: each thread computes float4 group tid and tid+T (T = total
//    threads) so every global load/store instruction is lane-contiguous (64*16B).
//  - Lower VGPR pressure (no 32 param VGPRs, 4-point groups) -> target <=64 VGPR,
//    8 waves/SIMD to hide exp2/fma chains.

__device__ __forceinline__ float bcast_f32(float v) {
    return __int_as_float(__builtin_amdgcn_readfirstlane(__float_as_int(v)));
}

__global__ __launch_bounds__(256) void gmm_hscore_kernel(
    const float* __restrict__ x,
    const float* __restrict__ mean,
    const float* __restrict__ logvar,
    const float* __restrict__ logweight,
    float* __restrict__ out,
    int n)
{
    // ---- uniform parameter setup: all lanes compute identical values, then
    // readfirstlane pins them in SGPRs (static indices keep arrays in regs) ----
    float s_mu[GMM_K], s_iv[GMM_K], s_c1[GMM_K], s_c2[GMM_K];
#pragma unroll
    for (int k = 0; k < GMM_K; ++k) {
        float lv = logvar[k];          // uniform address -> scalar load
        float lw = logweight[k];
        float mu = mean[k];
        float iv = __builtin_amdgcn_exp2f(-lv * LOG2E);   // exp(-lv)
        s_mu[k] = bcast_f32(mu);
        s_iv[k] = bcast_f32(iv);
        s_c1[k] = bcast_f32((lw - 0.5f * lv - HALF_LOG2PI) * LOG2E);
        s_c2[k] = bcast_f32(-0.5f * LOG2E * iv);
    }

    const int tid = blockIdx.x * blockDim.x + threadIdx.x;
    const int T   = gridDim.x * blockDim.x;     // total threads
    const int nv4 = n >> 2;                     // float4 groups

    const float4* __restrict__ xv = (const float4*)x;
    float4* __restrict__ ov = (float4*)out;

    // ---- two lane-contiguous float4 groups per thread: tid and tid+T ----
#pragma unroll
    for (int g = 0; g < 2; ++g) {
        const int idx = tid + g * T;
        if (idx < nv4) {
            float4 v = xv[idx];
            float xs[4] = {v.x, v.y, v.z, v.w};
            float res[4];
#pragma unroll
            for (int j = 0; j < 4; ++j) {
                float xx = xs[j];
                float m = 0.0f, md = 0.0f, dd = 0.0f;
#pragma unroll
                for (int k = 0; k < GMM_K; ++k) {
                    float diff = xx - s_mu[k];
                    float d2   = diff * diff;
                    float p    = __builtin_amdgcn_exp2f(
                                     __builtin_fmaf(s_c2[k], d2, s_c1[k]));
                    float sd   = diff * s_iv[k];
                    m  += p;
                    md = __builtin_fmaf(p, sd, md);
                    dd = __builtin_fmaf(p, __builtin_fmaf(sd, sd, -s_iv[k]), dd);
                }
                float inv_m = __builtin_amdgcn_rcpf(m);
                float dln   = md * inv_m;
                res[j] = __builtin_fmaf(-0.5f * dln, dln, dd * inv_m);
            }
            ov[idx] = make_float4(res[0], res[1], res[2], res[3]);
        }
    }

    // ---- scalar tail for n % 4 != 0 (not hit for N=4194304) ----
    if (tid == 0) {
        for (int i = nv4 << 2; i < n; ++i) {
            float xx = x[i];
            float m = 0.0f, md = 0.0f, dd = 0.0f;
            for (int k = 0; k < GMM_K; ++k) {
                float diff = xx - s_mu[k];
                float d2   = diff * diff;
                float p    = __builtin_amdgcn_exp2f(
                                 __builtin_fmaf(s_c2[k], d2, s_c1[k]));
                float sd   = diff * s_iv[k];
                m  += p;
                md = __builtin_fmaf(p, sd, md);
                dd = __builtin_fmaf(p, __builtin_fmaf(sd, sd, -s_iv[k]), dd);
            }
            float inv_m = __builtin_amdgcn_rcpf(m);
            float dln   = md * inv_m;
            out[i] = __builtin_fmaf(-0.5f * dln, dln, dd * inv_m);
        }
    }
}

extern "C" void kernel_launch(void* const* d_in, const int* in_sizes, int n_in,
                              void* d_out, int out_size, void* d_ws, size_t ws_size,
                              hipStream_t stream) {
    const float* x         = (const float*)d_in[0];
    const float* mean      = (const float*)d_in[1];
    const float* logvar    = (const float*)d_in[2];
    const float* logweight = (const float*)d_in[3];
    float* out = (float*)d_out;

    const int n   = in_sizes[0];               // 4194304 points
    const int nv4 = n >> 2;                    // 1048576 float4 groups
    // 2 groups (8 points) per thread, 256 threads/block
    const int groups_per_block = 256 * 2;
    const int grid = (nv4 + groups_per_block - 1) / groups_per_block;  // 2048

    gmm_hscore_kernel<<<grid, 256, 0, stream>>>(x, mean, logvar, logweight, out, n);
}